// Round 6
// baseline (1147.205 us; speedup 1.0000x reference)
//
#include <hip/hip_runtime.h>
#include <math.h>

#define NB 4
#define SEQ 4096
#define DM 512
#define NH 8
#define HD 64
#define UU 27
#define NG (NB*NH*UU)   // 864 selected (b,h,u) entries
#define NIDX (SEQ*UU)   // 110592
#define NC 32           // key chunks per (b,h) in attn_part
#define CS 128          // chunk size (keys)
#define PSTRIDE 66      // per-(bh,chunk,u) partial: m, l, acc[64]
#define GPB 8           // g-entries per proj_scatter block (864/8 = 108)

typedef unsigned int u32;
typedef unsigned short u16;
typedef __attribute__((ext_vector_type(8))) short short8;
typedef __attribute__((ext_vector_type(4))) float f32x4;

__host__ __device__ inline u32 rotl32(u32 x, u32 r){ return (x<<r)|(x>>(32u-r)); }

// Exact JAX threefry2x32 block cipher.
__host__ __device__ inline void threefry2x32(u32 k0, u32 k1, u32 x0, u32 x1, u32* o0, u32* o1)
{
  u32 ks[3] = { k0, k1, k0 ^ k1 ^ 0x1BD11BDAu };
  x0 += ks[0]; x1 += ks[1];
  const u32 rotA[4] = {13u,15u,26u,6u};
  const u32 rotB[4] = {17u,29u,16u,24u};
  for (int i = 0; i < 5; i++) {
    const u32* rot = (i & 1) ? rotB : rotA;
    for (int j = 0; j < 4; j++) { x0 += x1; x1 = rotl32(x1, rot[j]); x1 ^= x0; }
    x0 += ks[(i+1)%3];
    x1 += ks[(i+2)%3] + (u32)(i+1);
  }
  *o0 = x0; *o1 = x1;
}

__global__ __launch_bounds__(256) void gen_idx_kernel(u32 k2a, u32 k2b, int* __restrict__ idx)
{
  int i = blockIdx.x * 256 + threadIdx.x;
  if (i >= NIDX) return;
  u32 o0, o1;
  threefry2x32(k2a, k2b, 0u, (u32)i, &o0, &o1);
  idx[i] = (int)((o0 ^ o1) & (SEQ - 1));
}

__device__ inline u16 f2bf_rne(float f) {
  u32 u = __float_as_uint(f);
  return (u16)((u + 0x7fffu + ((u >> 16) & 1u)) >> 16);
}
// split: hi = RNE(f), lo = RNE(f - hi). hi+lo err ~ 2^-17 relative.
__device__ inline void f2bf_split(float f, u16& hi, u16& lo) {
  u16 h = f2bf_rne(f);
  float hf = __uint_as_float(((u32)h) << 16);
  hi = h;
  lo = f2bf_rne(f - hf);
}

// fp32 (16384x512) -> planar bf16 hi/lo. Memory-bound, 8 elems/thread.
__global__ __launch_bounds__(256) void conv_split(const float* __restrict__ X,
                                                  u16* __restrict__ hi, u16* __restrict__ lo)
{
  long g = (long)blockIdx.x * 256 + threadIdx.x;
  float4 x0 = ((const float4*)X)[g * 2];
  float4 x1 = ((const float4*)X)[g * 2 + 1];
  union { short8 v; u16 s[8]; } h, l;
  float xv[8] = { x0.x, x0.y, x0.z, x0.w, x1.x, x1.y, x1.z, x1.w };
  #pragma unroll
  for (int e = 0; e < 8; e++) f2bf_split(xv[e], h.s[e], l.s[e]);
  ((short8*)hi)[g] = h.v;
  ((short8*)lo)[g]  = l.v;
}

// 4 MFMA weights: W (512x512, k-major) -> W^T planes (n-major).
// hi planes contiguous (slots 1,2 = w0k,w0v -> fused K|V = 1024 rows).
struct WPtrs { const float* w[4]; };
__global__ __launch_bounds__(256) void convw_kernel(WPtrs wp, u16* __restrict__ outp)
{
  const int n  = blockIdx.x;
  const int wi = blockIdx.y;
  const float* W = wp.w[wi];
  u16* hi = outp + (long)wi * 262144 + n * DM;
  u16* lo = hi + 8L * 262144;
  for (int k = threadIdx.x; k < DM; k += 256) {
    u16 h, l;
    f2bf_split(W[(long)k * DM + n], h, l);
    hi[k] = h; lo[k] = l;
  }
}

// global -> LDS direct DMA, 16B per lane.
__device__ inline void gld16(const u16* g, short* l) {
  __builtin_amdgcn_global_load_lds((const u32*)g, (u32*)l, 16, 0, 0);
}

// Split MFMA GEMM (r3-measured structure: 64KB LDS, 2 blocks/CU, 0 conflicts,
// 2-slot dbuf with one overlapped prefetch step). C = A@W + bias, dual output
// (col<512 -> C0/bias0 else C1/bias1) for the fused K|V launch.
__global__ __launch_bounds__(256) void gemm_bf(
    const u16* __restrict__ Ah, const u16* __restrict__ Al,
    const u16* __restrict__ Wh, const u16* __restrict__ Wl,
    const float* __restrict__ bias0, const float* __restrict__ bias1,
    float* __restrict__ C0, float* __restrict__ C1)
{
  __shared__ short LB[2][4][4096];   // [dbuf][Ah,Wh,Al,Wl]

  const int t  = threadIdx.x;
  const int rb = blockIdx.x * 128;
  const int cb = blockIdx.y * 128;

  // staging source map (inverse of the LDS swizzle; r3-verified)
  const int slot = (t & 7) ^ ((t >> 3) & 7);
  const int c8   = slot & 3;
  const int rloc = ((t >> 3) << 1) + (slot >> 2);
  const u16* sAh = Ah + (long)(rb + rloc) * DM + c8 * 8;
  const u16* sWh = Wh + (long)(cb + rloc) * DM + c8 * 8;
  const u16* sAl = Al + (long)(rb + rloc) * DM + c8 * 8;
  const u16* sWl = Wl + (long)(cb + rloc) * DM + c8 * 8;
  const int w512 = (t >> 6) * 512;

  // fragment read offsets (swizzled; r3-verified 0 conflicts)
  const int lane = t & 63, wv = t >> 6;
  const int wm = (wv & 1) * 64, wn = (wv >> 1) * 64;
  const int fr = lane & 15, fq = lane >> 4;
  const int fsw = (fr >> 1) * 64 + ((((fr & 1) * 4 + fq) ^ (fr >> 1)) * 8);
  const int a_off = wm * 32 + fsw;
  const int b_off = wn * 32 + fsw;

  f32x4 acc[4][4];
  #pragma unroll
  for (int i = 0; i < 4; i++)
    #pragma unroll
    for (int j = 0; j < 4; j++) acc[i][j] = (f32x4)(0.f);

#define STAGE(buf, k0s) do { \
    gld16(sAh + (k0s),               &LB[buf][0][w512]); \
    gld16(sAh + (k0s) + 64 * DM,     &LB[buf][0][w512 + 2048]); \
    gld16(sWh + (k0s),               &LB[buf][1][w512]); \
    gld16(sWh + (k0s) + 64 * DM,     &LB[buf][1][w512 + 2048]); \
    gld16(sAl + (k0s),               &LB[buf][2][w512]); \
    gld16(sAl + (k0s) + 64 * DM,     &LB[buf][2][w512 + 2048]); \
    gld16(sWl + (k0s),               &LB[buf][3][w512]); \
    gld16(sWl + (k0s) + 64 * DM,     &LB[buf][3][w512 + 2048]); \
  } while (0)

  STAGE(0, 0);
  #pragma unroll 2
  for (int ks = 0; ks < 16; ks++) {
    const int cur = ks & 1;
    asm volatile("s_waitcnt vmcnt(0)" ::: "memory");
    __syncthreads();
    if (ks < 15) STAGE(cur ^ 1, (ks + 1) * 32);

    short8 a_hi[4], b_hi[4], a_lo[4], b_lo[4];
    #pragma unroll
    for (int i = 0; i < 4; i++) a_hi[i] = *(const short8*)&LB[cur][0][a_off + i * 512];
    #pragma unroll
    for (int j = 0; j < 4; j++) b_hi[j] = *(const short8*)&LB[cur][1][b_off + j * 512];
    #pragma unroll
    for (int i = 0; i < 4; i++) a_lo[i] = *(const short8*)&LB[cur][2][a_off + i * 512];
    #pragma unroll
    for (int j = 0; j < 4; j++) b_lo[j] = *(const short8*)&LB[cur][3][b_off + j * 512];

    #pragma unroll
    for (int i = 0; i < 4; i++)
      #pragma unroll
      for (int j = 0; j < 4; j++)
        acc[i][j] = __builtin_amdgcn_mfma_f32_16x16x32_bf16(a_hi[i], b_hi[j], acc[i][j], 0, 0, 0);
    #pragma unroll
    for (int i = 0; i < 4; i++)
      #pragma unroll
      for (int j = 0; j < 4; j++) {
        acc[i][j] = __builtin_amdgcn_mfma_f32_16x16x32_bf16(a_hi[i], b_lo[j], acc[i][j], 0, 0, 0);
        acc[i][j] = __builtin_amdgcn_mfma_f32_16x16x32_bf16(a_lo[i], b_hi[j], acc[i][j], 0, 0, 0);
      }
  }
#undef STAGE

  // epilogue: D layout col=lane&15, row=fq*4+reg
  #pragma unroll
  for (int j = 0; j < 4; j++) {
    int col = cb + wn + j * 16 + fr;
    const float* bp = (col < DM) ? bias0 : bias1;
    float* Cp = (col < DM) ? C0 : C1;
    int cc = col & (DM - 1);
    float bv = bp[cc];
    #pragma unroll
    for (int i = 0; i < 4; i++) {
      int row0 = rb + wm + i * 16 + fq * 4;
      #pragma unroll
      for (int r = 0; r < 4; r++) {
        int row = row0 + r;
        Cp[(long)row * DM + cc] = acc[i][j][r] + bv;
      }
    }
  }
}

// M[b,h,l] for ALL 8 heads by one wave per (b,l).
// L2-locality: 27 samples visited in 8 passes over 512-row K chunks.
__global__ __launch_bounds__(256) void mscore_kernel(const float* __restrict__ Q, const float* __restrict__ K,
                                                     const int* __restrict__ idx, float* __restrict__ M)
{
  const int wl = threadIdx.x >> 6, lane = threadIdx.x & 63;
  const int bl = blockIdx.x * 4 + wl;
  const int b = bl >> 12, l = bl & (SEQ - 1);

  const float4* qp = (const float4*)(Q + (long)bl * DM + lane * 8);
  float4 q0 = qp[0], q1 = qp[1];

  const int* ip = idx + l * UU;
  int idxv = ip[lane < UU ? lane : 0];
  int chv = idxv >> 9;

  const float* kb = K + ((long)b << 12) * DM + lane * 8;
  float mx = -INFINITY, sm = 0.f;
  #pragma unroll 1
  for (int c = 0; c < 8; c++) {
    unsigned long long msk = __ballot(chv == c) & ((1ull << UU) - 1ull);
    while (msk) {
      int s = __builtin_ctzll(msk);
      msk &= msk - 1;
      int kl = __shfl(idxv, s, 64);
      const float4* kp = (const float4*)(kb + (long)kl * DM);
      float4 k0 = kp[0], k1 = kp[1];
      float dot;
      dot = q0.x * k0.x;
      dot = fmaf(q0.y, k0.y, dot); dot = fmaf(q0.z, k0.z, dot); dot = fmaf(q0.w, k0.w, dot);
      dot = fmaf(q1.x, k1.x, dot); dot = fmaf(q1.y, k1.y, dot);
      dot = fmaf(q1.z, k1.z, dot); dot = fmaf(q1.w, k1.w, dot);
      dot += __shfl_xor(dot, 1, 64);
      dot += __shfl_xor(dot, 2, 64);
      dot += __shfl_xor(dot, 4, 64);
      mx = fmaxf(mx, dot);
      sm += dot;
    }
  }
  if ((lane & 7) == 0) {
    int h = lane >> 3;
    M[(((long)b * NH + h) << 12) + l] = mx - sm * (1.0f / (float)SEQ);
  }
}

// Stable top-27 of 4096 per (b,h). Ties: lower index first (lax.top_k).
__global__ __launch_bounds__(256) void topk_kernel(const float* __restrict__ M, int* __restrict__ topidx)
{
  __shared__ float vals[SEQ];
  __shared__ float rv[256];
  __shared__ int   ri[256];
  const float* m = M + (long)blockIdx.x * SEQ;
  for (int i = threadIdx.x; i < SEQ; i += 256) vals[i] = m[i];
  __syncthreads();
  for (int it = 0; it < UU; it++) {
    float bv = -INFINITY; int bi = 0x7fffffff;
    for (int i = threadIdx.x; i < SEQ; i += 256) {
      float v = vals[i];
      if (v > bv) { bv = v; bi = i; }
    }
    rv[threadIdx.x] = bv; ri[threadIdx.x] = bi;
    __syncthreads();
    for (int s = 128; s > 0; s >>= 1) {
      if (threadIdx.x < s) {
        float ov = rv[threadIdx.x + s]; int oi = ri[threadIdx.x + s];
        if (ov > rv[threadIdx.x] || (ov == rv[threadIdx.x] && oi < ri[threadIdx.x])) {
          rv[threadIdx.x] = ov; ri[threadIdx.x] = oi;
        }
      }
      __syncthreads();
    }
    if (threadIdx.x == 0) { topidx[blockIdx.x * UU + it] = ri[0]; vals[ri[0]] = -INFINITY; }
    __syncthreads();
  }
}

__global__ __launch_bounds__(512) void vmean_partial(const float* __restrict__ V, float* __restrict__ vsum)
{
  int b = blockIdx.x >> 5, chunk = blockIdx.x & 31;
  int c = threadIdx.x;
  const float* p = V + ((long)b * SEQ + chunk * 128) * DM + c;
  float s = 0.f;
  for (int l = 0; l < 128; l++) s += p[(long)l * DM];
  atomicAdd(&vsum[b * DM + c], s);
}

// Flash-style chunked attention for the 27 selected queries.
__global__ __launch_bounds__(256) void attn_part(const float* __restrict__ Q, const float* __restrict__ K,
                                                 const float* __restrict__ V, const int* __restrict__ topidx,
                                                 float* __restrict__ partial)
{
  __shared__ float Qs[UU][HD];
  __shared__ float S[UU][CS];
  __shared__ float Vt[CS][HD];
  __shared__ float m_s[UU], l_s[UU];

  const int t = threadIdx.x;
  const int bh = blockIdx.x;
  const int chunk = blockIdx.y;
  const int b = bh >> 3, h = bh & 7;
  const long kbase = ((long)(b << 12) + chunk * CS) * DM + h * HD;
  const int* tp = topidx + bh * UU;

  for (int i = t; i < UU * HD; i += 256) {
    int u = i >> 6, d = i & 63;
    Qs[u][d] = Q[((long)(b << 12) + tp[u]) * DM + h * HD + d];
  }
  for (int i = t; i < CS * (HD / 4); i += 256) {
    int row = i >> 4, c4 = (i & 15) << 2;
    *(float4*)&Vt[row][c4] = *(const float4*)(V + kbase + (long)row * DM + c4);
  }
  __syncthreads();

  {
    const int l = t >> 1, half = t & 1, d0 = half * 32;
    const float* kp = K + kbase + (long)l * DM + d0;
    float4 kr[8];
    #pragma unroll
    for (int j = 0; j < 8; j++) kr[j] = *(const float4*)(kp + j * 4);
    #pragma unroll 1
    for (int u = 0; u < UU; u++) {
      const float4* qf = (const float4*)&Qs[u][d0];
      float dot = 0.f;
      #pragma unroll
      for (int j = 0; j < 8; j++) {
        float4 q = qf[j];
        dot = fmaf(q.x, kr[j].x, dot); dot = fmaf(q.y, kr[j].y, dot);
        dot = fmaf(q.z, kr[j].z, dot); dot = fmaf(q.w, kr[j].w, dot);
      }
      float tot = dot + __shfl_xor(dot, 1, 64);
      if (half == 0) S[u][l] = tot * 0.125f;
    }
  }
  __syncthreads();

  {
    const int u = t >> 3, il = t & 7;
    if (u < UU) {
      float mx = -INFINITY;
      for (int l = il; l < CS; l += 8) mx = fmaxf(mx, S[u][l]);
      #pragma unroll
      for (int m = 1; m < 8; m <<= 1) mx = fmaxf(mx, __shfl_xor(mx, m, 64));
      float ps = 0.f;
      for (int l = il; l < CS; l += 8) {
        float e = expf(S[u][l] - mx);
        S[u][l] = e;
        ps += e;
      }
      #pragma unroll
      for (int m = 1; m < 8; m <<= 1) ps += __shfl_xor(ps, m, 64);
      if (il == 0) { m_s[u] = mx; l_s[u] = ps; }
    }
  }
  __syncthreads();

  {
    const int d = t & 63, g = t >> 6;
    for (int u = g; u < UU; u += 4) {
      float acc = 0.f;
      #pragma unroll 4
      for (int l = 0; l < CS; l += 4) {
        float4 p4 = *(const float4*)&S[u][l];
        acc = fmaf(p4.x, Vt[l][d],     acc);
        acc = fmaf(p4.y, Vt[l + 1][d], acc);
        acc = fmaf(p4.z, Vt[l + 2][d], acc);
        acc = fmaf(p4.w, Vt[l + 3][d], acc);
      }
      float* pp = partial + (((long)bh * NC + chunk) * UU + u) * PSTRIDE;
      pp[2 + d] = acc;
      if (d == 0) { pp[0] = m_s[u]; pp[1] = l_s[u]; }
    }
  }
}

// Merge partials -> compact out_top[g][64] (fp32).
__global__ __launch_bounds__(64) void attn_merge_c(const float* __restrict__ partial, float* __restrict__ otop)
{
  int g = blockIdx.x;
  int bh = g / UU, u = g % UU;
  int d = threadIdx.x;
  float M = -INFINITY, S = 0.f, acc = 0.f;
  for (int c = 0; c < NC; c++) {
    const float* pp = partial + (((long)bh * NC + c) * UU + u) * PSTRIDE;
    float mc = pp[0], sc = pp[1], a = pp[2 + d];
    if (mc > M) {
      float r = expf(M - mc);
      acc *= r; S *= r; M = mc;
    }
    float w = expf(mc - M);
    acc = fmaf(a, w, acc);
    S = fmaf(sc, w, S);
  }
  otop[(long)g * HD + d] = acc / S;
}

// xout[b] = (xin[b]*scale) @ W + bias   (fp32, per-batch row matvec).
// Optionally stores the scaled input row to ctx_store.
__global__ __launch_bounds__(256) void rowmv_kernel(const float* __restrict__ xin, float scale,
                                                    const float* __restrict__ W, const float* __restrict__ bias,
                                                    float* __restrict__ xout, float* __restrict__ ctx_store)
{
  int b = blockIdx.x;
  __shared__ float x[DM];
  for (int k = threadIdx.x; k < DM; k += 256) {
    float v = xin[b * DM + k] * scale;
    x[k] = v;
    if (ctx_store) ctx_store[b * DM + k] = v;
  }
  __syncthreads();
  for (int n0 = 0; n0 < DM; n0 += 256) {
    int n = n0 + threadIdx.x;
    float acc = bias[n];
    for (int k = 0; k < DM; k++) acc = fmaf(x[k], W[(long)k * DM + n], acc);
    xout[b * DM + n] = acc;
  }
}

// c[g] = (otop[g] - base_ctx[b][h*64..]) @ W[h*64.., :]   (head-slice matvec).
__global__ __launch_bounds__(256) void cproj_kernel(const float* __restrict__ otop, const float* __restrict__ base_ctx,
                                                    const float* __restrict__ W, float* __restrict__ c)
{
  int g = blockIdx.x; int bh = g / UU; int b = bh >> 3, h = bh & 7;
  __shared__ float dlt[HD];
  if (threadIdx.x < HD)
    dlt[threadIdx.x] = otop[(long)g * HD + threadIdx.x] - base_ctx[b * DM + h * HD + threadIdx.x];
  __syncthreads();
  for (int n0 = 0; n0 < DM; n0 += 256) {
    int n = n0 + threadIdx.x;
    float acc = 0.f;
    #pragma unroll 8
    for (int d = 0; d < HD; d++) acc = fmaf(dlt[d], W[(long)(h * HD + d) * DM + n], acc);
    c[(long)g * DM + n] = acc;
  }
}

// dst[b*SEQ + l] = base[b]  for all rows (broadcast 32MB write).
__global__ __launch_bounds__(256) void fill_rows(const float* __restrict__ base, float* __restrict__ dst)
{
  long g = (long)blockIdx.x * 256 + threadIdx.x;   // float4 index
  int b = (int)(g >> 19);
  ((float4*)dst)[g] = ((const float4*)base)[b * 128 + (int)(g & 127)];
}

// out lower half: out[b*8192 + l] = xs[b*8192 + l] + base[b].
__global__ __launch_bounds__(256) void fill_rows_resid(const float* __restrict__ base, const float* __restrict__ xs,
                                                       float* __restrict__ out)
{
  long g = (long)blockIdx.x * 256 + threadIdx.x;
  int b = (int)(g >> 19);
  long rem = g & 524287;
  long o = (long)b * (8192 * 128) + rem;
  float4 x = ((const float4*)xs)[o];
  float4 v = ((const float4*)base)[b * 128 + (int)(g & 127)];
  x.x += v.x; x.y += v.y; x.z += v.z; x.w += v.w;
  ((float4*)out)[o] = x;
}

// dst[row(g)] += c[g]   (atomic; rowPitch = rows per batch in dst).
__global__ __launch_bounds__(256) void scatter_add(const float* __restrict__ c, const int* __restrict__ topidx,
                                                   float* __restrict__ dst, int rowPitch)
{
  int g = blockIdx.x; int bh = g / UU, b = bh >> 3;
  int ql = topidx[g];
  float* row = dst + ((long)b * rowPitch + ql) * DM;
  const float* cg = c + (long)g * DM;
  for (int n = threadIdx.x; n < DM; n += 256) atomicAdd(&row[n], cg[n]);
}

// dst[row(g)] += c[g] @ W  (full 512x512 fp32 matvec; GPB entries share the W read).
__global__ __launch_bounds__(256) void proj_scatter(const float* __restrict__ c, const int* __restrict__ topidx,
                                                    const float* __restrict__ W, float* __restrict__ dst)
{
  int g0 = blockIdx.x * GPB;
  __shared__ float x[GPB][DM];
  for (int i = threadIdx.x; i < GPB * DM; i += 256)
    x[i >> 9][i & 511] = c[(long)g0 * DM + i];
  __syncthreads();
  for (int n0 = 0; n0 < DM; n0 += 256) {
    int n = n0 + threadIdx.x;
    float acc[GPB];
    #pragma unroll
    for (int j = 0; j < GPB; j++) acc[j] = 0.f;
    for (int k = 0; k < DM; k++) {
      float w = W[(long)k * DM + n];
      #pragma unroll
      for (int j = 0; j < GPB; j++) acc[j] = fmaf(x[j][k], w, acc[j]);
    }
    #pragma unroll
    for (int j = 0; j < GPB; j++) {
      int g = g0 + j;
      int bh = g / UU, b = bh >> 3;
      int ql = topidx[g];
      atomicAdd(&dst[((long)b * SEQ + ql) * DM + n], acc[j]);
    }
  }
}

__global__ __launch_bounds__(256) void add_upper(const float* __restrict__ xs, const float* __restrict__ xp2,
                                                 float* __restrict__ out)
{
  long g = (long)blockIdx.x * 256 + threadIdx.x;
  int b = (int)(g >> 19);
  long rem = g & 524287;
  float4 p = ((const float4*)xp2)[g];
  long o = ((long)b * 8192 + SEQ) * 128 + rem;
  float4 x = ((const float4*)xs)[o];
  x.x += p.x; x.y += p.y; x.z += p.z; x.w += p.w;
  ((float4*)out)[o] = x;
}

extern "C" void kernel_launch(void* const* d_in, const int* in_sizes, int n_in,
                              void* d_out, int out_size, void* d_ws, size_t ws_size,
                              hipStream_t stream)
{
  const float* xs  = (const float*)d_in[0];
  const float* xd  = (const float*)d_in[1];
  const float* xp  = (const float*)d_in[2];
  const float* w0q = (const float*)d_in[3];
  const float* w0k = (const float*)d_in[4];
  const float* w0v = (const float*)d_in[5];
  const float* w0o = (const float*)d_in[6];
  const float* b0q = (const float*)d_in[7];
  const float* b0k = (const float*)d_in[8];
  const float* b0v = (const float*)d_in[9];
  const float* b0o = (const float*)d_in[10];
  const float* w1q = (const float*)d_in[11];
  const float* w1k = (const float*)d_in[12];
  const float* w1v = (const float*)d_in[13];
  const float* w1o = (const float*)d_in[14];
  const float* b1q = (const float*)d_in[15];
  const float* b1k = (const float*)d_in[16];
  const float* b1v = (const float*)d_in[17];
  const float* b1o = (const float*)d_in[18];
  float* out = (float*)d_out;

  const long BIG = (long)NB * SEQ * DM;   // 8 Mi floats = 32 MB
  float* A  = (float*)d_ws;   // Q0 / Q1
  float* Bb = A  + BIG;       // K0, then xp2
  float* Cc = Bb + BIG;       // V0, then K1
  float* Dd = Cc + BIG;       // V1
  float* ex = Dd + BIG;       // scratch region (32 MB)
  float* Pq  = ex + BIG;      // plane pair 1: hi | lo (bf16)
  float* Pkv = Pq + BIG;      // plane pair 2

  int*   idxbuf  = (int*)ex;                       // 110592 ints
  float* Mbuf    = ex + 131072;                    // 131072 floats
  int*   topidx0 = (int*)(ex + 262144);            // 864
  int*   topidx1 = (int*)(ex + 263168);            // 864
  float* vsum    = ex + 264192;                    // 2048
  float* bctx0   = ex + 266240;                    // 2048 (base ctx = vmean)
  float* bout0   = ex + 268288;                    // 2048 (base_out layer0 = xp2 base)
  float* bK1     = ex + 270336;
  float* bV1     = ex + 272384;
  float* bctx1   = ex + 274432;
  float* bout1   = ex + 276480;
  float* otop    = ex + 278528;                    // 864*64
  float* cbuf    = ex + (1L << 19);                // 864*512
  u16*   wpl     = (u16*)(ex + (1L << 20));        // 8 MB weight planes (4 slots used)
  float* partials= ex + 3L * (1L << 20);           // 7.3 MB

  u16* Pq_hi  = (u16*)Pq;   u16* Pq_lo  = Pq_hi  + BIG;
  u16* Pkv_hi = (u16*)Pkv;  u16* Pkv_lo = Pkv_hi + BIG;
  auto whi = [&](int i){ return wpl + (long)i * 262144; };
  auto wlo = [&](int i){ return wpl + 8L * 262144 + (long)i * 262144; };

  dim3 gg(128, 4);     // 512-col GEMM
  dim3 gkv(128, 8);    // fused K|V GEMM (1024 cols)
  dim3 ag(NB * NH, NC);
  u32 k2a, k2b;

  // one-time: W^T hi/lo planes for the 4 MFMA weights (w0q, w0k, w0v, w1q)
  WPtrs wp;
  wp.w[0] = w0q; wp.w[1] = w0k; wp.w[2] = w0v; wp.w[3] = w1q;
  convw_kernel<<<dim3(512, 4), 256, 0, stream>>>(wp, wpl);

  // ---------- layer 0: xp2 = attn_layer(q=xp; kv=xd), key 42 ----------
  threefry2x32(0u, 42u, 0u, 1u, &k2a, &k2b);
  gen_idx_kernel<<<(NIDX + 255) / 256, 256, 0, stream>>>(k2a, k2b, idxbuf);
  conv_split<<<4096, 256, 0, stream>>>(xp, Pq_hi, Pq_lo);
  conv_split<<<4096, 256, 0, stream>>>(xd, Pkv_hi, Pkv_lo);
  gemm_bf<<<gg,  256, 0, stream>>>(Pq_hi,  Pq_lo,  whi(0), wlo(0), b0q, b0q, A,  A);   // Q0
  gemm_bf<<<gkv, 256, 0, stream>>>(Pkv_hi, Pkv_lo, whi(1), wlo(1), b0k, b0v, Bb, Cc);  // K0->Bb, V0->Cc
  mscore_kernel<<<NB * SEQ / 4, 256, 0, stream>>>(A, Bb, idxbuf, Mbuf);
  topk_kernel<<<NB * NH, 256, 0, stream>>>(Mbuf, topidx0);
  hipMemsetAsync(vsum, 0, NB * DM * sizeof(float), stream);
  vmean_partial<<<NB * 32, 512, 0, stream>>>(Cc, vsum);
  attn_part<<<ag, 256, 0, stream>>>(A, Bb, Cc, topidx0, partials);
  attn_merge_c<<<NG, 64, 0, stream>>>(partials, otop);
  // O-projection collapse: base row per batch (fp32) + 864 sparse head-slice corrections
  rowmv_kernel<<<NB, 256, 0, stream>>>(vsum, 1.0f / (float)SEQ, w0o, b0o, bout0, bctx0);
  cproj_kernel<<<NG, 256, 0, stream>>>(otop, bctx0, w0o, cbuf);
  fill_rows<<<8192, 256, 0, stream>>>(bout0, Bb);                 // xp2 = broadcast base (over K0)
  scatter_add<<<NG, 256, 0, stream>>>(cbuf, topidx0, Bb, SEQ);    // + sparse corrections
  add_upper<<<8192, 256, 0, stream>>>(xs, Bb, out);               // out upper = xs + xp2

  // ---------- layer 1: xd2 = attn_layer(q=xd; kv=xp2), key 43 ----------
  threefry2x32(0u, 43u, 0u, 1u, &k2a, &k2b);
  gen_idx_kernel<<<(NIDX + 255) / 256, 256, 0, stream>>>(k2a, k2b, idxbuf);
  gemm_bf<<<gg, 256, 0, stream>>>(Pkv_hi, Pkv_lo, whi(3), wlo(3), b1q, b1q, A, A);     // Q1 (xd planes)
  // K1/V1 collapse: xp2 = base + sparse  =>  K1 = base@W1k + sparse@W1k (same for V1)
  rowmv_kernel<<<NB, 256, 0, stream>>>(bout0, 1.0f, w1k, b1k, bK1, nullptr);
  rowmv_kernel<<<NB, 256, 0, stream>>>(bout0, 1.0f, w1v, b1v, bV1, nullptr);
  fill_rows<<<8192, 256, 0, stream>>>(bK1, Cc);
  fill_rows<<<8192, 256, 0, stream>>>(bV1, Dd);
  proj_scatter<<<NG / GPB, 256, 0, stream>>>(cbuf, topidx0, w1k, Cc);
  proj_scatter<<<NG / GPB, 256, 0, stream>>>(cbuf, topidx0, w1v, Dd);
  mscore_kernel<<<NB * SEQ / 4, 256, 0, stream>>>(A, Cc, idxbuf, Mbuf);
  topk_kernel<<<NB * NH, 256, 0, stream>>>(Mbuf, topidx1);
  hipMemsetAsync(vsum, 0, NB * DM * sizeof(float), stream);
  vmean_partial<<<NB * 32, 512, 0, stream>>>(Dd, vsum);
  attn_part<<<ag, 256, 0, stream>>>(A, Cc, Dd, topidx1, partials);
  attn_merge_c<<<NG, 64, 0, stream>>>(partials, otop);
  rowmv_kernel<<<NB, 256, 0, stream>>>(vsum, 1.0f / (float)SEQ, w1o, b1o, bout1, bctx1);
  cproj_kernel<<<NG, 256, 0, stream>>>(otop, bctx1, w1o, cbuf);
  fill_rows_resid<<<8192, 256, 0, stream>>>(bout1, xs, out);      // out lower = xs + base
  scatter_add<<<NG, 256, 0, stream>>>(cbuf, topidx1, out, 8192);  // + sparse corrections
}

// Round 7
// 800.106 us; speedup vs baseline: 1.4338x; 1.4338x over previous
//
#include <hip/hip_runtime.h>
#include <math.h>

#define NB 4
#define SEQ 4096
#define DM 512
#define NH 8
#define HD 64
#define UU 27
#define NG (NB*NH*UU)   // 864 selected (b,h,u) entries
#define NIDX (SEQ*UU)   // 110592
#define NC 32           // key chunks per (b,h) in attn_part
#define CS 128          // chunk size (keys)
#define PSTRIDE 66      // per-(bh,chunk,u) partial: m, l, acc[64]

typedef unsigned int u32;
typedef unsigned short u16;
typedef __attribute__((ext_vector_type(8))) short short8;
typedef __attribute__((ext_vector_type(4))) float f32x4;

__host__ __device__ inline u32 rotl32(u32 x, u32 r){ return (x<<r)|(x>>(32u-r)); }

// Exact JAX threefry2x32 block cipher.
__host__ __device__ inline void threefry2x32(u32 k0, u32 k1, u32 x0, u32 x1, u32* o0, u32* o1)
{
  u32 ks[3] = { k0, k1, k0 ^ k1 ^ 0x1BD11BDAu };
  x0 += ks[0]; x1 += ks[1];
  const u32 rotA[4] = {13u,15u,26u,6u};
  const u32 rotB[4] = {17u,29u,16u,24u};
  for (int i = 0; i < 5; i++) {
    const u32* rot = (i & 1) ? rotB : rotA;
    for (int j = 0; j < 4; j++) { x0 += x1; x1 = rotl32(x1, rot[j]); x1 ^= x0; }
    x0 += ks[(i+1)%3];
    x1 += ks[(i+2)%3] + (u32)(i+1);
  }
  *o0 = x0; *o1 = x1;
}

__global__ __launch_bounds__(256) void gen_idx_kernel(u32 k2a, u32 k2b, int* __restrict__ idx)
{
  int i = blockIdx.x * 256 + threadIdx.x;
  if (i >= NIDX) return;
  u32 o0, o1;
  threefry2x32(k2a, k2b, 0u, (u32)i, &o0, &o1);
  idx[i] = (int)((o0 ^ o1) & (SEQ - 1));
}

__device__ inline u16 f2bf_rne(float f) {
  u32 u = __float_as_uint(f);
  return (u16)((u + 0x7fffu + ((u >> 16) & 1u)) >> 16);
}
// split: hi = RNE(f), lo = RNE(f - hi). hi+lo err ~ 2^-17 relative.
__device__ inline void f2bf_split(float f, u16& hi, u16& lo) {
  u16 h = f2bf_rne(f);
  float hf = __uint_as_float(((u32)h) << 16);
  hi = h;
  lo = f2bf_rne(f - hf);
}

// fp32 row-major matrix -> planar bf16 hi/lo. 8 elems/thread; grid covers size/2048.
__global__ __launch_bounds__(256) void conv_split(const float* __restrict__ X,
                                                  u16* __restrict__ hi, u16* __restrict__ lo)
{
  long g = (long)blockIdx.x * 256 + threadIdx.x;
  float4 x0 = ((const float4*)X)[g * 2];
  float4 x1 = ((const float4*)X)[g * 2 + 1];
  union { short8 v; u16 s[8]; } h, l;
  float xv[8] = { x0.x, x0.y, x0.z, x0.w, x1.x, x1.y, x1.z, x1.w };
  #pragma unroll
  for (int e = 0; e < 8; e++) f2bf_split(xv[e], h.s[e], l.s[e]);
  ((short8*)hi)[g] = h.v;
  ((short8*)lo)[g]  = l.v;
}

// 6 MFMA weights: W (512x512, k-major) -> W^T planes (n-major).
// hi planes contiguous: slots 1,2 = w0k,w0v (fused K|V), slots 4,5 = w1k,w1v (fused Wc).
struct WPtrs { const float* w[6]; };
__global__ __launch_bounds__(256) void convw_kernel(WPtrs wp, u16* __restrict__ outp)
{
  const int n  = blockIdx.x;
  const int wi = blockIdx.y;
  const float* W = wp.w[wi];
  u16* hi = outp + (long)wi * 262144 + n * DM;
  u16* lo = hi + 8L * 262144;
  for (int k = threadIdx.x; k < DM; k += 256) {
    u16 h, l;
    f2bf_split(W[(long)k * DM + n], h, l);
    hi[k] = h; lo[k] = l;
  }
}

// global -> LDS direct DMA, 16B per lane.
__device__ inline void gld16(const u16* g, short* l) {
  __builtin_amdgcn_global_load_lds((const u32*)g, (u32*)l, 16, 0, 0);
}

// Split MFMA GEMM (r3-measured structure: 64KB LDS, 2 blocks/CU, 0 conflicts).
// C = A@W + bias, dual output (col<512 -> C0/bias0 else C1/bias1).
__global__ __launch_bounds__(256) void gemm_bf(
    const u16* __restrict__ Ah, const u16* __restrict__ Al,
    const u16* __restrict__ Wh, const u16* __restrict__ Wl,
    const float* __restrict__ bias0, const float* __restrict__ bias1,
    float* __restrict__ C0, float* __restrict__ C1)
{
  __shared__ short LB[2][4][4096];   // [dbuf][Ah,Wh,Al,Wl]

  const int t  = threadIdx.x;
  const int rb = blockIdx.x * 128;
  const int cb = blockIdx.y * 128;

  // staging source map (inverse of the LDS swizzle; r3-verified)
  const int slot = (t & 7) ^ ((t >> 3) & 7);
  const int c8   = slot & 3;
  const int rloc = ((t >> 3) << 1) + (slot >> 2);
  const u16* sAh = Ah + (long)(rb + rloc) * DM + c8 * 8;
  const u16* sWh = Wh + (long)(cb + rloc) * DM + c8 * 8;
  const u16* sAl = Al + (long)(rb + rloc) * DM + c8 * 8;
  const u16* sWl = Wl + (long)(cb + rloc) * DM + c8 * 8;
  const int w512 = (t >> 6) * 512;

  // fragment read offsets (swizzled; r3-verified 0 conflicts)
  const int lane = t & 63, wv = t >> 6;
  const int wm = (wv & 1) * 64, wn = (wv >> 1) * 64;
  const int fr = lane & 15, fq = lane >> 4;
  const int fsw = (fr >> 1) * 64 + ((((fr & 1) * 4 + fq) ^ (fr >> 1)) * 8);
  const int a_off = wm * 32 + fsw;
  const int b_off = wn * 32 + fsw;

  f32x4 acc[4][4];
  #pragma unroll
  for (int i = 0; i < 4; i++)
    #pragma unroll
    for (int j = 0; j < 4; j++) acc[i][j] = (f32x4)(0.f);

#define STAGE(buf, k0s) do { \
    gld16(sAh + (k0s),               &LB[buf][0][w512]); \
    gld16(sAh + (k0s) + 64 * DM,     &LB[buf][0][w512 + 2048]); \
    gld16(sWh + (k0s),               &LB[buf][1][w512]); \
    gld16(sWh + (k0s) + 64 * DM,     &LB[buf][1][w512 + 2048]); \
    gld16(sAl + (k0s),               &LB[buf][2][w512]); \
    gld16(sAl + (k0s) + 64 * DM,     &LB[buf][2][w512 + 2048]); \
    gld16(sWl + (k0s),               &LB[buf][3][w512]); \
    gld16(sWl + (k0s) + 64 * DM,     &LB[buf][3][w512 + 2048]); \
  } while (0)

  STAGE(0, 0);
  #pragma unroll 2
  for (int ks = 0; ks < 16; ks++) {
    const int cur = ks & 1;
    asm volatile("s_waitcnt vmcnt(0)" ::: "memory");
    __syncthreads();
    if (ks < 15) STAGE(cur ^ 1, (ks + 1) * 32);

    short8 a_hi[4], b_hi[4], a_lo[4], b_lo[4];
    #pragma unroll
    for (int i = 0; i < 4; i++) a_hi[i] = *(const short8*)&LB[cur][0][a_off + i * 512];
    #pragma unroll
    for (int j = 0; j < 4; j++) b_hi[j] = *(const short8*)&LB[cur][1][b_off + j * 512];
    #pragma unroll
    for (int i = 0; i < 4; i++) a_lo[i] = *(const short8*)&LB[cur][2][a_off + i * 512];
    #pragma unroll
    for (int j = 0; j < 4; j++) b_lo[j] = *(const short8*)&LB[cur][3][b_off + j * 512];

    #pragma unroll
    for (int i = 0; i < 4; i++)
      #pragma unroll
      for (int j = 0; j < 4; j++)
        acc[i][j] = __builtin_amdgcn_mfma_f32_16x16x32_bf16(a_hi[i], b_hi[j], acc[i][j], 0, 0, 0);
    #pragma unroll
    for (int i = 0; i < 4; i++)
      #pragma unroll
      for (int j = 0; j < 4; j++) {
        acc[i][j] = __builtin_amdgcn_mfma_f32_16x16x32_bf16(a_hi[i], b_lo[j], acc[i][j], 0, 0, 0);
        acc[i][j] = __builtin_amdgcn_mfma_f32_16x16x32_bf16(a_lo[i], b_hi[j], acc[i][j], 0, 0, 0);
      }
  }
#undef STAGE

  // epilogue: D layout col=lane&15, row=fq*4+reg
  #pragma unroll
  for (int j = 0; j < 4; j++) {
    int col = cb + wn + j * 16 + fr;
    const float* bp = (col < DM) ? bias0 : bias1;
    float* Cp = (col < DM) ? C0 : C1;
    int cc = col & (DM - 1);
    float bv = bp[cc];
    #pragma unroll
    for (int i = 0; i < 4; i++) {
      int row0 = rb + wm + i * 16 + fq * 4;
      #pragma unroll
      for (int r = 0; r < 4; r++) {
        int row = row0 + r;
        Cp[(long)row * DM + cc] = acc[i][j][r] + bv;
      }
    }
  }
}

// M[b,h,l] for ALL 8 heads by one wave per (b,l).
// L2-locality: 27 samples visited in 8 passes over 512-row K chunks.
__global__ __launch_bounds__(256) void mscore_kernel(const float* __restrict__ Q, const float* __restrict__ K,
                                                     const int* __restrict__ idx, float* __restrict__ M)
{
  const int wl = threadIdx.x >> 6, lane = threadIdx.x & 63;
  const int bl = blockIdx.x * 4 + wl;
  const int b = bl >> 12, l = bl & (SEQ - 1);

  const float4* qp = (const float4*)(Q + (long)bl * DM + lane * 8);
  float4 q0 = qp[0], q1 = qp[1];

  const int* ip = idx + l * UU;
  int idxv = ip[lane < UU ? lane : 0];
  int chv = idxv >> 9;

  const float* kb = K + ((long)b << 12) * DM + lane * 8;
  float mx = -INFINITY, sm = 0.f;
  #pragma unroll 1
  for (int c = 0; c < 8; c++) {
    unsigned long long msk = __ballot(chv == c) & ((1ull << UU) - 1ull);
    while (msk) {
      int s = __builtin_ctzll(msk);
      msk &= msk - 1;
      int kl = __shfl(idxv, s, 64);
      const float4* kp = (const float4*)(kb + (long)kl * DM);
      float4 k0 = kp[0], k1 = kp[1];
      float dot;
      dot = q0.x * k0.x;
      dot = fmaf(q0.y, k0.y, dot); dot = fmaf(q0.z, k0.z, dot); dot = fmaf(q0.w, k0.w, dot);
      dot = fmaf(q1.x, k1.x, dot); dot = fmaf(q1.y, k1.y, dot);
      dot = fmaf(q1.z, k1.z, dot); dot = fmaf(q1.w, k1.w, dot);
      dot += __shfl_xor(dot, 1, 64);
      dot += __shfl_xor(dot, 2, 64);
      dot += __shfl_xor(dot, 4, 64);
      mx = fmaxf(mx, dot);
      sm += dot;
    }
  }
  if ((lane & 7) == 0) {
    int h = lane >> 3;
    M[(((long)b * NH + h) << 12) + l] = mx - sm * (1.0f / (float)SEQ);
  }
}

// Stable top-27 of 4096 per (b,h). Ties: lower index first (lax.top_k).
__global__ __launch_bounds__(256) void topk_kernel(const float* __restrict__ M, int* __restrict__ topidx)
{
  __shared__ float vals[SEQ];
  __shared__ float rv[256];
  __shared__ int   ri[256];
  const float* m = M + (long)blockIdx.x * SEQ;
  for (int i = threadIdx.x; i < SEQ; i += 256) vals[i] = m[i];
  __syncthreads();
  for (int it = 0; it < UU; it++) {
    float bv = -INFINITY; int bi = 0x7fffffff;
    for (int i = threadIdx.x; i < SEQ; i += 256) {
      float v = vals[i];
      if (v > bv) { bv = v; bi = i; }
    }
    rv[threadIdx.x] = bv; ri[threadIdx.x] = bi;
    __syncthreads();
    for (int s = 128; s > 0; s >>= 1) {
      if (threadIdx.x < s) {
        float ov = rv[threadIdx.x + s]; int oi = ri[threadIdx.x + s];
        if (ov > rv[threadIdx.x] || (ov == rv[threadIdx.x] && oi < ri[threadIdx.x])) {
          rv[threadIdx.x] = ov; ri[threadIdx.x] = oi;
        }
      }
      __syncthreads();
    }
    if (threadIdx.x == 0) { topidx[blockIdx.x * UU + it] = ri[0]; vals[ri[0]] = -INFINITY; }
    __syncthreads();
  }
}

__global__ __launch_bounds__(512) void vmean_partial(const float* __restrict__ V, float* __restrict__ vsum)
{
  int b = blockIdx.x >> 5, chunk = blockIdx.x & 31;
  int c = threadIdx.x;
  const float* p = V + ((long)b * SEQ + chunk * 128) * DM + c;
  float s = 0.f;
  for (int l = 0; l < 128; l++) s += p[(long)l * DM];
  atomicAdd(&vsum[b * DM + c], s);
}

// Flash-style chunked attention for the 27 selected queries.
__global__ __launch_bounds__(256) void attn_part(const float* __restrict__ Q, const float* __restrict__ K,
                                                 const float* __restrict__ V, const int* __restrict__ topidx,
                                                 float* __restrict__ partial)
{
  __shared__ float Qs[UU][HD];
  __shared__ float S[UU][CS];
  __shared__ float Vt[CS][HD];
  __shared__ float m_s[UU], l_s[UU];

  const int t = threadIdx.x;
  const int bh = blockIdx.x;
  const int chunk = blockIdx.y;
  const int b = bh >> 3, h = bh & 7;
  const long kbase = ((long)(b << 12) + chunk * CS) * DM + h * HD;
  const int* tp = topidx + bh * UU;

  for (int i = t; i < UU * HD; i += 256) {
    int u = i >> 6, d = i & 63;
    Qs[u][d] = Q[((long)(b << 12) + tp[u]) * DM + h * HD + d];
  }
  for (int i = t; i < CS * (HD / 4); i += 256) {
    int row = i >> 4, c4 = (i & 15) << 2;
    *(float4*)&Vt[row][c4] = *(const float4*)(V + kbase + (long)row * DM + c4);
  }
  __syncthreads();

  {
    const int l = t >> 1, half = t & 1, d0 = half * 32;
    const float* kp = K + kbase + (long)l * DM + d0;
    float4 kr[8];
    #pragma unroll
    for (int j = 0; j < 8; j++) kr[j] = *(const float4*)(kp + j * 4);
    #pragma unroll 1
    for (int u = 0; u < UU; u++) {
      const float4* qf = (const float4*)&Qs[u][d0];
      float dot = 0.f;
      #pragma unroll
      for (int j = 0; j < 8; j++) {
        float4 q = qf[j];
        dot = fmaf(q.x, kr[j].x, dot); dot = fmaf(q.y, kr[j].y, dot);
        dot = fmaf(q.z, kr[j].z, dot); dot = fmaf(q.w, kr[j].w, dot);
      }
      float tot = dot + __shfl_xor(dot, 1, 64);
      if (half == 0) S[u][l] = tot * 0.125f;
    }
  }
  __syncthreads();

  {
    const int u = t >> 3, il = t & 7;
    if (u < UU) {
      float mx = -INFINITY;
      for (int l = il; l < CS; l += 8) mx = fmaxf(mx, S[u][l]);
      #pragma unroll
      for (int m = 1; m < 8; m <<= 1) mx = fmaxf(mx, __shfl_xor(mx, m, 64));
      float ps = 0.f;
      for (int l = il; l < CS; l += 8) {
        float e = expf(S[u][l] - mx);
        S[u][l] = e;
        ps += e;
      }
      #pragma unroll
      for (int m = 1; m < 8; m <<= 1) ps += __shfl_xor(ps, m, 64);
      if (il == 0) { m_s[u] = mx; l_s[u] = ps; }
    }
  }
  __syncthreads();

  {
    const int d = t & 63, g = t >> 6;
    for (int u = g; u < UU; u += 4) {
      float acc = 0.f;
      #pragma unroll 4
      for (int l = 0; l < CS; l += 4) {
        float4 p4 = *(const float4*)&S[u][l];
        acc = fmaf(p4.x, Vt[l][d],     acc);
        acc = fmaf(p4.y, Vt[l + 1][d], acc);
        acc = fmaf(p4.z, Vt[l + 2][d], acc);
        acc = fmaf(p4.w, Vt[l + 3][d], acc);
      }
      float* pp = partial + (((long)bh * NC + chunk) * UU + u) * PSTRIDE;
      pp[2 + d] = acc;
      if (d == 0) { pp[0] = m_s[u]; pp[1] = l_s[u]; }
    }
  }
}

// Merge partials -> compact out_top[g][64] (fp32).
__global__ __launch_bounds__(64) void attn_merge_c(const float* __restrict__ partial, float* __restrict__ otop)
{
  int g = blockIdx.x;
  int bh = g / UU, u = g % UU;
  int d = threadIdx.x;
  float M = -INFINITY, S = 0.f, acc = 0.f;
  for (int c = 0; c < NC; c++) {
    const float* pp = partial + (((long)bh * NC + c) * UU + u) * PSTRIDE;
    float mc = pp[0], sc = pp[1], a = pp[2 + d];
    if (mc > M) {
      float r = expf(M - mc);
      acc *= r; S *= r; M = mc;
    }
    float w = expf(mc - M);
    acc = fmaf(a, w, acc);
    S = fmaf(sc, w, S);
  }
  otop[(long)g * HD + d] = acc / S;
}

// xout[b] = (xin[b]*scale) @ W + bias. Parallel: grid (NB, 4), 128 cols/block,
// 2-way k-split + LDS reduce. Block y==0 optionally stores scaled input.
__global__ __launch_bounds__(256) void rowmv_kernel(const float* __restrict__ xin, float scale,
                                                    const float* __restrict__ W, const float* __restrict__ bias,
                                                    float* __restrict__ xout, float* __restrict__ ctx_store)
{
  int b = blockIdx.x, nt = blockIdx.y;
  __shared__ float x[DM];
  __shared__ float red[256];
  for (int k = threadIdx.x; k < DM; k += 256) {
    float v = xin[b * DM + k] * scale;
    x[k] = v;
    if (ctx_store && nt == 0) ctx_store[b * DM + k] = v;
  }
  __syncthreads();
  int n = nt * 128 + (threadIdx.x & 127);
  int kh = threadIdx.x >> 7;
  float acc = 0.f;
  #pragma unroll 8
  for (int k = kh * 256; k < kh * 256 + 256; k++) acc = fmaf(x[k], W[(long)k * DM + n], acc);
  red[threadIdx.x] = acc;
  __syncthreads();
  if (threadIdx.x < 128)
    xout[b * DM + n] = red[threadIdx.x] + red[threadIdx.x + 128] + bias[n];
}

// Fused correction projection + scatter:
//   dst[b*rowPitch + rowOff + topidx[g]] += (otop[g] - bctx[b][h*64..]) @ W[h*64.., :]
// One block per g; 64x512 head-slice matvec; atomicAdd handles multi-h rows.
__global__ __launch_bounds__(256) void cproj_scatter(const float* __restrict__ otop, const float* __restrict__ bctx,
                                                     const int* __restrict__ topidx, const float* __restrict__ W,
                                                     float* __restrict__ dst, int rowPitch, int rowOff)
{
  int g = blockIdx.x; int bh = g / UU; int b = bh >> 3, h = bh & 7;
  __shared__ float dlt[HD];
  if (threadIdx.x < HD)
    dlt[threadIdx.x] = otop[(long)g * HD + threadIdx.x] - bctx[b * DM + h * HD + threadIdx.x];
  __syncthreads();
  int ql = topidx[g];
  float* row = dst + ((long)b * rowPitch + rowOff + ql) * DM;
  for (int n0 = 0; n0 < DM; n0 += 256) {
    int n = n0 + threadIdx.x;
    float acc = 0.f;
    #pragma unroll 8
    for (int d = 0; d < HD; d++) acc = fmaf(dlt[d], W[(long)(h * HD + d) * DM + n], acc);
    atomicAdd(&row[n], acc);
  }
}

// dst[b*SEQ + l] = base[b]  for all rows (broadcast 32MB write).
__global__ __launch_bounds__(256) void fill_rows(const float* __restrict__ base, float* __restrict__ dst)
{
  long g = (long)blockIdx.x * 256 + threadIdx.x;   // float4 index
  int b = (int)(g >> 19);
  ((float4*)dst)[g] = ((const float4*)base)[b * 128 + (int)(g & 127)];
}

// out[b*8192 + off + l] = xs[b*8192 + off + l] + base[b]  (4096 rows per batch).
__global__ __launch_bounds__(256) void fill_resid(const float* __restrict__ base, const float* __restrict__ xs,
                                                  float* __restrict__ out, int off)
{
  long g = (long)blockIdx.x * 256 + threadIdx.x;
  int b = (int)(g >> 19);
  long rem = g & 524287;
  long o = ((long)b * 8192 + off) * 128 + rem;
  float4 x = ((const float4*)xs)[o];
  float4 v = ((const float4*)base)[b * 128 + (int)(g & 127)];
  x.x += v.x; x.y += v.y; x.z += v.z; x.w += v.w;
  ((float4*)out)[o] = x;
}

extern "C" void kernel_launch(void* const* d_in, const int* in_sizes, int n_in,
                              void* d_out, int out_size, void* d_ws, size_t ws_size,
                              hipStream_t stream)
{
  const float* xs  = (const float*)d_in[0];
  const float* xd  = (const float*)d_in[1];
  const float* xp  = (const float*)d_in[2];
  const float* w0q = (const float*)d_in[3];
  const float* w0k = (const float*)d_in[4];
  const float* w0v = (const float*)d_in[5];
  const float* w0o = (const float*)d_in[6];
  const float* b0q = (const float*)d_in[7];
  const float* b0k = (const float*)d_in[8];
  const float* b0v = (const float*)d_in[9];
  const float* b0o = (const float*)d_in[10];
  const float* w1q = (const float*)d_in[11];
  const float* w1k = (const float*)d_in[12];
  const float* w1v = (const float*)d_in[13];
  const float* w1o = (const float*)d_in[14];
  const float* b1q = (const float*)d_in[15];
  const float* b1k = (const float*)d_in[16];
  const float* b1v = (const float*)d_in[17];
  const float* b1o = (const float*)d_in[18];
  float* out = (float*)d_out;

  const long BIG = (long)NB * SEQ * DM;   // 8 Mi floats = 32 MB
  float* A  = (float*)d_ws;   // Q0 / Q1
  float* Bb = A  + BIG;       // K0
  float* Cc = Bb + BIG;       // V0, then K1
  float* Dd = Cc + BIG;       // V1
  float* ex = Dd + BIG;       // scratch region (32 MB)
  float* Pq  = ex + BIG;      // plane pair 1: hi | lo (bf16)
  float* Pkv = Pq + BIG;      // plane pair 2

  int*   idxbuf  = (int*)ex;                       // 110592 ints
  float* Mbuf    = ex + 131072;                    // 131072 floats
  int*   topidx0 = (int*)(ex + 262144);            // 864
  int*   topidx1 = (int*)(ex + 263168);            // 864
  float* vsum    = ex + 264192;                    // 2048
  float* bctx0   = ex + 266240;
  float* bout0   = ex + 268288;
  float* bK1     = ex + 270336;
  float* bV1     = ex + 272384;
  float* bctx1   = ex + 274432;
  float* bout1   = ex + 276480;
  float* otop    = ex + 278528;                    // 864*64
  float* zerob   = ex + 335872;                    // 512 zeros
  float* Wck     = ex + 524288;                    // 512x512 fp32 = W0o@W1k
  float* Wcv     = ex + 786432;                    // 512x512 fp32 = W0o@W1v
  u16*   wpl     = (u16*)(ex + 1048576);           // 8 MB: 8 hi plane slots + 8 lo (6 used)
  float* partials= ex + 3145728;                   // 7.3 MB
  u16*   W0oh    = (u16*)(ex + 5242880);           // W0o as A-planes (row-major)
  u16*   W0ol    = W0oh + 262144;

  u16* Pq_hi  = (u16*)Pq;   u16* Pq_lo  = Pq_hi  + BIG;
  u16* Pkv_hi = (u16*)Pkv;  u16* Pkv_lo = Pkv_hi + BIG;
  auto whi = [&](int i){ return wpl + (long)i * 262144; };
  auto wlo = [&](int i){ return wpl + 8L * 262144 + (long)i * 262144; };

  dim3 gg(128, 4);     // 512-col GEMM
  dim3 gkv(128, 8);    // fused dual-output GEMM (1024 cols)
  dim3 ag(NB * NH, NC);
  dim3 rmv(NB, 4);
  u32 k2a, k2b;

  // ---------- one-time: weight planes + composite Wc = W0o@W1{k,v} ----------
  WPtrs wp;
  wp.w[0] = w0q; wp.w[1] = w0k; wp.w[2] = w0v; wp.w[3] = w1q; wp.w[4] = w1k; wp.w[5] = w1v;
  convw_kernel<<<dim3(512, 6), 256, 0, stream>>>(wp, wpl);
  conv_split<<<128, 256, 0, stream>>>(w0o, W0oh, W0ol);          // W0o as GEMM A-operand
  hipMemsetAsync(zerob, 0, DM * sizeof(float), stream);
  gemm_bf<<<dim3(4, 8), 256, 0, stream>>>(W0oh, W0ol, whi(4), wlo(4), zerob, zerob, Wck, Wcv);

  // ---------- layer 0: xp2 = attn_layer(q=xp; kv=xd), key 42 ----------
  threefry2x32(0u, 42u, 0u, 1u, &k2a, &k2b);
  gen_idx_kernel<<<(NIDX + 255) / 256, 256, 0, stream>>>(k2a, k2b, idxbuf);
  conv_split<<<4096, 256, 0, stream>>>(xp, Pq_hi, Pq_lo);
  conv_split<<<4096, 256, 0, stream>>>(xd, Pkv_hi, Pkv_lo);
  gemm_bf<<<gg,  256, 0, stream>>>(Pq_hi,  Pq_lo,  whi(0), wlo(0), b0q, b0q, A,  A);   // Q0
  gemm_bf<<<gkv, 256, 0, stream>>>(Pkv_hi, Pkv_lo, whi(1), wlo(1), b0k, b0v, Bb, Cc);  // K0->Bb, V0->Cc
  mscore_kernel<<<NB * SEQ / 4, 256, 0, stream>>>(A, Bb, idxbuf, Mbuf);
  topk_kernel<<<NB * NH, 256, 0, stream>>>(Mbuf, topidx0);
  hipMemsetAsync(vsum, 0, NB * DM * sizeof(float), stream);
  vmean_partial<<<NB * 32, 512, 0, stream>>>(Cc, vsum);
  attn_part<<<ag, 256, 0, stream>>>(A, Bb, Cc, topidx0, partials);
  attn_merge_c<<<NG, 64, 0, stream>>>(partials, otop);
  rowmv_kernel<<<rmv, 256, 0, stream>>>(vsum, 1.0f / (float)SEQ, w0o, b0o, bout0, bctx0);
  // out upper = xs + base xp2 + sparse corrections (xp2 never materialized)
  fill_resid<<<8192, 256, 0, stream>>>(bout0, xs, out, SEQ);
  cproj_scatter<<<NG, 256, 0, stream>>>(otop, bctx0, topidx0, w0o, out, 8192, SEQ);

  // ---------- layer 1: xd2 = attn_layer(q=xd; kv=xp2), key 43 ----------
  threefry2x32(0u, 43u, 0u, 1u, &k2a, &k2b);
  gen_idx_kernel<<<(NIDX + 255) / 256, 256, 0, stream>>>(k2a, k2b, idxbuf);
  gemm_bf<<<gg, 256, 0, stream>>>(Pkv_hi, Pkv_lo, whi(3), wlo(3), b1q, b1q, A, A);     // Q1 (xd planes)
  // K1/V1 = broadcast base + composite sparse corrections (xp2 never materialized)
  rowmv_kernel<<<rmv, 256, 0, stream>>>(bout0, 1.0f, w1k, b1k, bK1, nullptr);
  rowmv_kernel<<<rmv, 256, 0, stream>>>(bout0, 1.0f, w1v, b1v, bV1, nullptr);
  fill_rows<<<8192, 256, 0, stream>>>(bK1, Cc);
  fill_rows<<<8192, 256, 0, stream>>>(bV1, Dd);
  cproj_scatter<<<NG, 256, 0, stream>>>(otop, bctx0, topidx0, Wck, Cc, SEQ, 0);
  cproj_scatter<<<NG, 256, 0, stream>>>(otop, bctx0, topidx0, Wcv, Dd, SEQ, 0);
  mscore_kernel<<<NB * SEQ / 4, 256, 0, stream>>>(A, Cc, idxbuf, Mbuf);
  topk_kernel<<<NB * NH, 256, 0, stream>>>(Mbuf, topidx1);
  hipMemsetAsync(vsum, 0, NB * DM * sizeof(float), stream);
  vmean_partial<<<NB * 32, 512, 0, stream>>>(Dd, vsum);
  attn_part<<<ag, 256, 0, stream>>>(A, Cc, Dd, topidx1, partials);
  attn_merge_c<<<NG, 64, 0, stream>>>(partials, otop);
  rowmv_kernel<<<rmv, 256, 0, stream>>>(vsum, 1.0f / (float)SEQ, w1o, b1o, bout1, bctx1);
  fill_resid<<<8192, 256, 0, stream>>>(bout1, xs, out, 0);
  cproj_scatter<<<NG, 256, 0, stream>>>(otop, bctx1, topidx1, w1o, out, 8192, 0);
}